// Round 16
// baseline (42.034 us; speedup 1.0000x reference)
//
#include <hip/hip_runtime.h>
#include <hip/hip_bf16.h>

#define NBINS 32
#define CHUNK 128           // voxels per chunk per block
#define NROWS 34            // rows 1..32 = bins 0..31; rows 0/33 = clamp garbage
#define STR 136             // halfs per row; 272B stride: every row 16B-aligned
#define TILE_HALVES (NROWS * STR)   // 4624 halfs = 9248 B per tile
#define NTHREADS 256
#define NVOX 884736         // 96^3 = 6912 * 128
#define BPB 768             // grid (768,2) = 1536 blocks = exactly 6/CU
#define NCHUNKS 9           // 768 * 9 = 6912 slabs -> perfectly uniform, no tail
#define NSLOTS 16
#define NBLOCKS (2 * BPB)

typedef __attribute__((ext_vector_type(8))) _Float16 half8;
typedef __attribute__((ext_vector_type(16))) float f32x16;
typedef __attribute__((ext_vector_type(4))) int i32x4;

// Parzen 6-tap window — BIT-IDENTICAL math to the validated R4-R15 kernels.
__device__ __forceinline__ void compute_w(float x, int& kb, _Float16* wq) {
    float tt = x * 31.0f;
    float kf = rintf(tt);
    int ki = (int)kf;
    float u = tt - kf;               // [-0.5, 0.5]
    kb = ki - 3 + (u > 0.0f ? 1 : 0);
    float w[6];
    float s = 0.0f;
#pragma unroll
    for (int o = 0; o < 6; ++o) {
        int b = kb + o;
        float d = tt - (float)b;
        float e = __expf(-2.0f * d * d);
        e = ((unsigned)b < NBINS) ? e : 0.0f;
        w[o] = e;
        s += e;
    }
    float rinv = 1.0f / s;
#pragma unroll
    for (int o = 0; o < 6; ++o) wq[o] = (_Float16)(w[o] * rinv);
}

// Unconditional clamped writes: OOB taps land in garbage rows 0/33 (never read).
__device__ __forceinline__ void zero6(_Float16* __restrict__ L, int col, int kb) {
#pragma unroll
    for (int o = 0; o < 6; ++o) {
        int r = min(max(kb + o, -1), 32) + 1;
        L[r * STR + col] = (_Float16)0.0f;
    }
}
__device__ __forceinline__ void scatter6(_Float16* __restrict__ L, int col, int kb,
                                         const _Float16* wq) {
#pragma unroll
    for (int o = 0; o < 6; ++o) {
        int r = min(max(kb + o, -1), 32) + 1;
        L[r * STR + col] = wq[o];
    }
}

__global__ __launch_bounds__(NTHREADS, 6)
void mi_hist_kernel(const float* __restrict__ pred, const float* __restrict__ targ,
                    float* __restrict__ hist /* [NSLOTS][2][32][32] */,
                    int* __restrict__ counter, float* __restrict__ out) {
    // SINGLE tile pair (A,B): 18496 B -> 6 blocks/CU
    __shared__ __attribute__((aligned(16))) _Float16 smem[2 * TILE_HALVES];
    __shared__ int s_last;
    _Float16* TA = smem;
    _Float16* TB = smem + TILE_HALVES;

    const int tid = threadIdx.x;
    const int bx = blockIdx.x;
    const int batch = blockIdx.y;
    const int col = tid & 127;
    const float* src = (tid >= 128 ? targ : pred) + (size_t)batch * NVOX;
    _Float16* T = smem + (tid >> 7) * TILE_HALVES;   // 0-127 -> TA, 128-255 -> TB

    const int wid = tid >> 6;
    const int lane = tid & 63;
    // mfma_f32_32x32x16_f16: row(col)=lane&31 (bin b -> row b+1), wave wid owns K [wid*32,+32)
    const int frag = (1 + (lane & 31)) * STR + wid * 32 + 8 * (lane >> 5);

    // preload ALL 9 chunk values -> no vmem in the main loop
    float xs[NCHUNKS];
#pragma unroll
    for (int c = 0; c < NCHUNKS; ++c)
        xs[c] = src[((size_t)(c * BPB + bx)) * CHUNK + col];

    // zero both tiles once (2*4624/8 = 1156 b128)
    {
        i32x4 z = {0, 0, 0, 0};
        i32x4* zp = (i32x4*)smem;
#pragma unroll
        for (int i = 0; i < 5; ++i) {
            int idx = i * NTHREADS + tid;
            if (idx < (2 * TILE_HALVES) / 8) zp[idx] = z;
        }
    }

    f32x16 acc;
#pragma unroll
    for (int r = 0; r < 16; ++r) acc[r] = 0.0f;

    int kb_old = 0;

#define DO_MFMA() { \
        _Pragma("unroll") \
        for (int kk = 0; kk < 2; ++kk) { \
            half8 af = *(const half8*)&TA[frag + kk * 16]; \
            half8 bf = *(const half8*)&TB[frag + kk * 16]; \
            acc = __builtin_amdgcn_mfma_f32_32x32x16_f16(af, bf, acc, 0, 0, 0); \
        } }

    // chunk 0 (no stale taps yet)
    {
        _Float16 wq[6]; int kb;
        compute_w(xs[0], kb, wq);
        __syncthreads();                 // prologue zero visible
        scatter6(T, col, kb, wq);
        kb_old = kb;
        __syncthreads();                 // scatter visible
        DO_MFMA();
    }
#pragma unroll
    for (int c = 1; c < NCHUNKS; ++c) {
        _Float16 wq[6]; int kb;
        compute_w(xs[c], kb, wq);        // VALU overlaps MFMA pipe + other blocks' LDS phases
        __syncthreads();                 // prev MFMA ds_reads drained (WAR safe)
        zero6(T, col, kb_old);           // stale taps from chunk c-1
        scatter6(T, col, kb, wq);
        kb_old = kb;
        __syncthreads();                 // scatter visible
        DO_MFMA();
    }
    __syncthreads();                     // last MFMA reads drained before smem reuse

    // block reduce: 4 waves hold K-split partials of the SAME 32x32.
    // C/D layout (32x32): col = lane&31, row = (reg&3) + 8*(reg>>2) + 4*(lane>>5)
    float* red = (float*)smem;           // 4 * 1024 floats = 16 KB (fits 18.5 KB)
    const int colc = lane & 31;
    const int rlo = 4 * (lane >> 5);
#pragma unroll
    for (int r = 0; r < 16; ++r) {
        int rowc = (r & 3) + 8 * (r >> 2) + rlo;
        red[wid * 1024 + rowc * 32 + colc] = acc[r];
    }
    __syncthreads();
    float* H = hist + ((size_t)(bx & (NSLOTS - 1)) * 2 + batch) * 1024;
    for (int idx = tid; idx < 1024; idx += NTHREADS) {
        float s = red[idx] + red[1024 + idx] + red[2048 + idx] + red[3072 + idx];
        atomicAdd(&H[idx], s);          // device-scope RMW -> coherent point, no fence needed
    }

    // ---- last-block fused MI reduction (NO __threadfence: the __syncthreads()
    // below compiles to s_waitcnt vmcnt(0) per wave + s_barrier, so every hist
    // atomic of this block is at the coherent point before the counter bump). ----
    __syncthreads();
    if (tid == 0) {
        int old = __hip_atomic_fetch_add(counter, 1, __ATOMIC_RELAXED,
                                         __HIP_MEMORY_SCOPE_AGENT);
        s_last = (old == NBLOCKS - 1);
    }
    __syncthreads();
    if (!s_last) return;

    // carve reducer scratch from smem
    float* s_pab = (float*)smem;                       // 2048 f = 8192 B
    double* s_pa = (double*)((char*)smem + 8192);      // 64 d
    double* s_pb = (double*)((char*)smem + 8704);      // 64 d
    double* s_red = (double*)((char*)smem + 9216);     // 256 d
    const double invN = 1.0 / (double)NVOX;

    for (int idx = tid; idx < 2048; idx += NTHREADS) {
        float s = 0.0f;
        for (int sl = 0; sl < NSLOTS; ++sl)            // same order -> bit-identical
            s += __hip_atomic_load(&hist[sl * 2048 + idx], __ATOMIC_RELAXED,
                                   __HIP_MEMORY_SCOPE_AGENT);
        s_pab[idx] = s;
    }
    __syncthreads();

    if (tid < 64) {
        int b = tid >> 5, i = tid & 31;
        double s = 0.0;
        for (int j = 0; j < NBINS; ++j) s += (double)s_pab[(b * NBINS + i) * NBINS + j];
        s_pa[b * NBINS + i] = s * invN;
    } else if (tid < 128) {
        int t2 = tid - 64;
        int b = t2 >> 5, j = t2 & 31;
        double s = 0.0;
        for (int i = 0; i < NBINS; ++i) s += (double)s_pab[(b * NBINS + i) * NBINS + j];
        s_pb[b * NBINS + j] = s * invN;
    }
    __syncthreads();

    double accd = 0.0;
    for (int idx = tid; idx < 2048; idx += NTHREADS) {
        int b = idx >> 10;
        int cell = idx & 1023;
        int i = cell >> 5, j = cell & 31;
        double pab = (double)s_pab[idx] * invN;
        double papb = s_pa[b * NBINS + i] * s_pb[b * NBINS + j];
        accd += pab * log((pab + 1e-7) / (papb + 1e-7) + 1e-7);
    }
    s_red[tid] = accd;
    __syncthreads();
    for (int s2 = 128; s2 > 0; s2 >>= 1) {
        if (tid < s2) s_red[tid] += s_red[tid + s2];
        __syncthreads();
    }
    if (tid == 0) out[0] = (float)(-0.5 * s_red[0]);
}

extern "C" void kernel_launch(void* const* d_in, const int* in_sizes, int n_in,
                              void* d_out, int out_size, void* d_ws, size_t ws_size,
                              hipStream_t stream) {
    const float* pred = (const float*)d_in[0];
    const float* targ = (const float*)d_in[1];
    float* hist = (float*)d_ws;
    int* counter = (int*)((char*)d_ws + NSLOTS * 2048 * sizeof(float));
    float* out = (float*)d_out;

    hipMemsetAsync(d_ws, 0, NSLOTS * 2048 * sizeof(float) + 16, stream);
    dim3 grid(BPB, 2);
    hipLaunchKernelGGL(mi_hist_kernel, grid, dim3(NTHREADS), 0, stream,
                       pred, targ, hist, counter, out);
}

// Round 17
// 31.145 us; speedup vs baseline: 1.3496x; 1.3496x over previous
//
#include <hip/hip_runtime.h>
#include <hip/hip_bf16.h>

#define NBINS 32
#define CHUNK 128           // voxels per chunk per block
#define NROWS 34            // rows 1..32 = bins 0..31; rows 0/33 = clamp garbage
#define STR 128             // halfs per row (256B). XOR-swizzle fixes banks on both sides.
#define TILE_HALVES (NROWS * STR)   // 4352 halfs = 8704 B per tile
#define NTHREADS 256
#define NVOX 884736         // 96^3 = 6912 * 128
#define BPB 768             // grid (768,2) = 1536 blocks = exactly 6/CU
#define NCHUNKS 9           // 768 * 9 = 6912 slabs -> perfectly uniform, no tail
#define NSLOTS 16

typedef __attribute__((ext_vector_type(8))) _Float16 half8;
typedef __attribute__((ext_vector_type(16))) float f32x16;
typedef __attribute__((ext_vector_type(4))) int i32x4;

// Swizzled half-offset for element (row r, col c):
//   off = r*128 + (c ^ ((r&7)<<4))
// - bijective per row (XOR on bits 4-6 of the col index)
// - WRITES (fixed c, random r): bank = (c>>1) ^ {0,8,16,24} -> <=2-way (free)
// - READS (b128, r = 1+(lane&31)): 8-half groups stay contiguous & 16B-aligned
//   (XOR bits 4-6 only); start banks span 8 groups -> minimum 8 accesses/bank.
__device__ __forceinline__ int swz(int r, int c) {
    return (r << 7) + (c ^ ((r & 7) << 4));
}

// Parzen 6-tap window — BIT-IDENTICAL math to the validated R4-R16 kernels.
__device__ __forceinline__ void compute_w(float x, int& kb, _Float16* wq) {
    float tt = x * 31.0f;
    float kf = rintf(tt);
    int ki = (int)kf;
    float u = tt - kf;               // [-0.5, 0.5]
    kb = ki - 3 + (u > 0.0f ? 1 : 0);
    float w[6];
    float s = 0.0f;
#pragma unroll
    for (int o = 0; o < 6; ++o) {
        int b = kb + o;
        float d = tt - (float)b;
        float e = __expf(-2.0f * d * d);
        e = ((unsigned)b < NBINS) ? e : 0.0f;
        w[o] = e;
        s += e;
    }
    float rinv = 1.0f / s;
#pragma unroll
    for (int o = 0; o < 6; ++o) wq[o] = (_Float16)(w[o] * rinv);
}

// Unconditional clamped writes: OOB taps land in garbage rows 0/33 (never read).
__device__ __forceinline__ void zero6(_Float16* __restrict__ L, int col, int kb) {
#pragma unroll
    for (int o = 0; o < 6; ++o) {
        int r = min(max(kb + o, -1), 32) + 1;
        L[swz(r, col)] = (_Float16)0.0f;
    }
}
__device__ __forceinline__ void scatter6(_Float16* __restrict__ L, int col, int kb,
                                         const _Float16* wq) {
#pragma unroll
    for (int o = 0; o < 6; ++o) {
        int r = min(max(kb + o, -1), 32) + 1;
        L[swz(r, col)] = wq[o];
    }
}

__global__ __launch_bounds__(NTHREADS, 6)
void mi_hist_kernel(const float* __restrict__ pred, const float* __restrict__ targ,
                    float* __restrict__ hist /* [NSLOTS][2][32][32] */) {
    // SINGLE tile pair (A,B): 17408 B -> 6 blocks/CU (104 KB)
    __shared__ __attribute__((aligned(16))) _Float16 smem[2 * TILE_HALVES];
    _Float16* TA = smem;
    _Float16* TB = smem + TILE_HALVES;

    const int tid = threadIdx.x;
    const int bx = blockIdx.x;
    const int batch = blockIdx.y;
    const int col = tid & 127;
    const float* src = (tid >= 128 ? targ : pred) + (size_t)batch * NVOX;
    _Float16* T = smem + (tid >> 7) * TILE_HALVES;   // 0-127 -> TA, 128-255 -> TB

    const int wid = tid >> 6;
    const int lane = tid & 63;
    // mfma_f32_32x32x16_f16: row(col)=lane&31 (bin b -> row b+1), wave wid owns K [wid*32,+32)
    const int rrow = 1 + (lane & 31);
    const int fbase = wid * 32 + 8 * (lane >> 5);    // half index within row, pre-swizzle
    const int frag0 = swz(rrow, fbase);              // kk=0 fragment (8 contiguous halfs)
    const int frag1 = swz(rrow, fbase + 16);         // kk=1 fragment

    // preload ALL 9 chunk values -> no vmem in the main loop
    float xs[NCHUNKS];
#pragma unroll
    for (int c = 0; c < NCHUNKS; ++c)
        xs[c] = src[((size_t)(c * BPB + bx)) * CHUNK + col];

    // zero both tiles once (2*4352/8 = 1088 b128), swizzle-agnostic
    {
        i32x4 z = {0, 0, 0, 0};
        i32x4* zp = (i32x4*)smem;
#pragma unroll
        for (int i = 0; i < 5; ++i) {
            int idx = i * NTHREADS + tid;
            if (idx < (2 * TILE_HALVES) / 8) zp[idx] = z;
        }
    }

    f32x16 acc;
#pragma unroll
    for (int r = 0; r < 16; ++r) acc[r] = 0.0f;

    int kb_old = 0;

#define DO_MFMA() { \
        half8 af0 = *(const half8*)&TA[frag0]; \
        half8 bf0 = *(const half8*)&TB[frag0]; \
        acc = __builtin_amdgcn_mfma_f32_32x32x16_f16(af0, bf0, acc, 0, 0, 0); \
        half8 af1 = *(const half8*)&TA[frag1]; \
        half8 bf1 = *(const half8*)&TB[frag1]; \
        acc = __builtin_amdgcn_mfma_f32_32x32x16_f16(af1, bf1, acc, 0, 0, 0); \
    }

    // chunk 0 (no stale taps yet)
    {
        _Float16 wq[6]; int kb;
        compute_w(xs[0], kb, wq);
        __syncthreads();                 // prologue zero visible
        scatter6(T, col, kb, wq);
        kb_old = kb;
        __syncthreads();                 // scatter visible
        DO_MFMA();
    }
#pragma unroll
    for (int c = 1; c < NCHUNKS; ++c) {
        _Float16 wq[6]; int kb;
        compute_w(xs[c], kb, wq);        // VALU overlaps MFMA pipe + other blocks' LDS phases
        __syncthreads();                 // prev MFMA ds_reads drained (WAR safe)
        zero6(T, col, kb_old);           // stale taps from chunk c-1
        scatter6(T, col, kb, wq);
        kb_old = kb;
        __syncthreads();                 // scatter visible
        DO_MFMA();
    }
    __syncthreads();                     // last MFMA reads drained before smem reuse

    // block reduce: 4 waves hold K-split partials of the SAME 32x32.
    // C/D layout (32x32): col = lane&31, row = (reg&3) + 8*(reg>>2) + 4*(lane>>5)
    float* red = (float*)smem;           // 4 * 1024 floats = 16 KB (fits 17.4 KB)
    const int colc = lane & 31;
    const int rlo = 4 * (lane >> 5);
#pragma unroll
    for (int r = 0; r < 16; ++r) {
        int rowc = (r & 3) + 8 * (r >> 2) + rlo;
        red[wid * 1024 + rowc * 32 + colc] = acc[r];
    }
    __syncthreads();
    float* H = hist + ((size_t)(bx & (NSLOTS - 1)) * 2 + batch) * 1024;
    for (int idx = tid; idx < 1024; idx += NTHREADS) {
        float s = red[idx] + red[1024 + idx] + red[2048 + idx] + red[3072 + idx];
        atomicAdd(&H[idx], s);
    }
}

__global__ void mi_reduce_kernel(const float* __restrict__ hist, float* __restrict__ out) {
    __shared__ float s_pab[2 * NBINS * NBINS];
    __shared__ double s_pa[2][NBINS];
    __shared__ double s_pb[2][NBINS];
    __shared__ double s_red[1024];
    const int tid = threadIdx.x;
    const double invN = 1.0 / (double)NVOX;

    for (int g = tid; g < 512; g += 1024) {
        float4 s = make_float4(0.f, 0.f, 0.f, 0.f);
        for (int sl = 0; sl < NSLOTS; ++sl) {
            float4 v = ((const float4*)hist)[sl * 512 + g];
            s.x += v.x; s.y += v.y; s.z += v.z; s.w += v.w;
        }
        ((float4*)s_pab)[g] = s;
    }
    __syncthreads();

    if (tid < 64) {
        int b = tid >> 5, i = tid & 31;
        double s = 0.0;
        for (int j = 0; j < NBINS; ++j) s += (double)s_pab[(b * NBINS + i) * NBINS + j];
        s_pa[b][i] = s * invN;
    } else if (tid < 128) {
        int t2 = tid - 64;
        int b = t2 >> 5, j = t2 & 31;
        double s = 0.0;
        for (int i = 0; i < NBINS; ++i) s += (double)s_pab[(b * NBINS + i) * NBINS + j];
        s_pb[b][j] = s * invN;
    }
    __syncthreads();

    double acc = 0.0;
    for (int idx = tid; idx < 2 * NBINS * NBINS; idx += 1024) {
        int b = idx >> 10;
        int cell = idx & 1023;
        int i = cell >> 5, j = cell & 31;
        double pab = (double)s_pab[idx] * invN;
        double papb = s_pa[b][i] * s_pb[b][j];
        acc += pab * log((pab + 1e-7) / (papb + 1e-7) + 1e-7);
    }
    s_red[tid] = acc;
    __syncthreads();
    for (int s2 = 512; s2 > 0; s2 >>= 1) {
        if (tid < s2) s_red[tid] += s_red[tid + s2];
        __syncthreads();
    }
    if (tid == 0) out[0] = (float)(-0.5 * s_red[0]);
}

extern "C" void kernel_launch(void* const* d_in, const int* in_sizes, int n_in,
                              void* d_out, int out_size, void* d_ws, size_t ws_size,
                              hipStream_t stream) {
    const float* pred = (const float*)d_in[0];
    const float* targ = (const float*)d_in[1];
    float* hist = (float*)d_ws;
    float* out = (float*)d_out;

    hipMemsetAsync(hist, 0, NSLOTS * 2 * NBINS * NBINS * sizeof(float), stream);
    dim3 grid(BPB, 2);
    hipLaunchKernelGGL(mi_hist_kernel, grid, dim3(NTHREADS), 0, stream, pred, targ, hist);
    hipLaunchKernelGGL(mi_reduce_kernel, dim3(1), dim3(1024), 0, stream, hist, out);
}

// Round 18
// 30.037 us; speedup vs baseline: 1.3994x; 1.0369x over previous
//
#include <hip/hip_runtime.h>
#include <hip/hip_bf16.h>

#define NBINS 32
#define CHUNK 128           // voxels per chunk per block
#define NROWS 34            // rows 1..32 = bins 0..31; rows 0/33 = clamp garbage
#define STR 136             // halfs per row; 272B stride: every row 16B-aligned
#define TILE_HALVES (NROWS * STR)   // 4624 halfs = 9248 B per tile
#define NTHREADS 256
#define NVOX 884736         // 96^3 = 6912 * 128
#define BPB 768             // grid (768,2) = 1536 blocks = exactly 6/CU
#define NCHUNKS 9           // 768 * 9 = 6912 slabs -> perfectly uniform, no tail
#define NSLOTS 16

typedef __attribute__((ext_vector_type(8))) _Float16 half8;
typedef __attribute__((ext_vector_type(16))) float f32x16;
typedef __attribute__((ext_vector_type(4))) int i32x4;

// Parzen 6-tap window, exp-reduced form. Exact-arithmetic-equal to the R4-R17
// direct form: exp(-2(u-g)^2) = exp(-2u^2) * t^g * e^{-2g^2}, t=e^{4u};
// the common factors exp(-2u^2) and t^s cancel in the normalization, so
// w_o ∝ c[o+s] * t^o * t^s with c = e^{-2g^2} constants. 1 exp instead of 6.
__device__ __forceinline__ void compute_w(float x, int& kb, _Float16* wq) {
    float tt = x * 31.0f;
    float kf = rintf(tt);
    int ki = (int)kf;
    float u = tt - kf;               // [-0.5, 0.5]
    const bool sp = (u > 0.0f);
    kb = ki - 3 + (sp ? 1 : 0);

    float t1 = __expf(4.0f * u);
    float t2 = t1 * t1;
    float t3 = t2 * t1;
    float t4 = t2 * t2;
    float t5 = t3 * t2;
    float ts = sp ? t1 : 1.0f;
    // c[g+3] for g=-3..3: e^-18, e^-8, e^-2, 1, e^-2, e^-8, e^-18
    const float c0 = 1.50343918e-8f;   // e^-18
    const float c1 = 3.35462628e-4f;   // e^-8
    const float c2 = 1.35335283e-1f;   // e^-2
    const float c3 = 1.0f;

    float w[6];
    float s = 0.0f;
    // e_o = c[o+s] * t^o * ts, masked by bin range (same predicate as before)
    {
        float p0 = 1.0f, p1 = t1, p2 = t2, p3 = t3, p4 = t4, p5 = t5;
        float e;
        e = (sp ? c1 : c0) * p0 * ts; e = ((unsigned)(kb + 0) < NBINS) ? e : 0.0f; w[0] = e; s += e;
        e = (sp ? c2 : c1) * p1 * ts; e = ((unsigned)(kb + 1) < NBINS) ? e : 0.0f; w[1] = e; s += e;
        e = (sp ? c3 : c2) * p2 * ts; e = ((unsigned)(kb + 2) < NBINS) ? e : 0.0f; w[2] = e; s += e;
        e = (sp ? c2 : c3) * p3 * ts; e = ((unsigned)(kb + 3) < NBINS) ? e : 0.0f; w[3] = e; s += e;
        e = (sp ? c1 : c2) * p4 * ts; e = ((unsigned)(kb + 4) < NBINS) ? e : 0.0f; w[4] = e; s += e;
        e = (sp ? c0 : c1) * p5 * ts; e = ((unsigned)(kb + 5) < NBINS) ? e : 0.0f; w[5] = e; s += e;
    }
    float rinv = 1.0f / s;
#pragma unroll
    for (int o = 0; o < 6; ++o) wq[o] = (_Float16)(w[o] * rinv);
}

// Unconditional clamped writes: OOB taps land in garbage rows 0/33 (never read).
__device__ __forceinline__ void zero6(_Float16* __restrict__ L, int col, int kb) {
#pragma unroll
    for (int o = 0; o < 6; ++o) {
        int r = min(max(kb + o, -1), 32) + 1;
        L[r * STR + col] = (_Float16)0.0f;
    }
}
__device__ __forceinline__ void scatter6(_Float16* __restrict__ L, int col, int kb,
                                         const _Float16* wq) {
#pragma unroll
    for (int o = 0; o < 6; ++o) {
        int r = min(max(kb + o, -1), 32) + 1;
        L[r * STR + col] = wq[o];
    }
}

__global__ __launch_bounds__(NTHREADS, 6)
void mi_hist_kernel(const float* __restrict__ pred, const float* __restrict__ targ,
                    float* __restrict__ hist /* [NSLOTS][2][32][32] */) {
    // SINGLE tile pair (A,B): 18496 B -> 6 blocks/CU
    __shared__ __attribute__((aligned(16))) _Float16 smem[2 * TILE_HALVES];
    _Float16* TA = smem;
    _Float16* TB = smem + TILE_HALVES;

    const int tid = threadIdx.x;
    const int bx = blockIdx.x;
    const int batch = blockIdx.y;
    const int col = tid & 127;
    const float* src = (tid >= 128 ? targ : pred) + (size_t)batch * NVOX;
    _Float16* T = smem + (tid >> 7) * TILE_HALVES;   // 0-127 -> TA, 128-255 -> TB

    const int wid = tid >> 6;
    const int lane = tid & 63;
    // mfma_f32_32x32x16_f16: row(col)=lane&31 (bin b -> row b+1), wave wid owns K [wid*32,+32)
    const int frag = (1 + (lane & 31)) * STR + wid * 32 + 8 * (lane >> 5);

    // preload ALL 9 chunk values -> no vmem in the main loop
    float xs[NCHUNKS];
#pragma unroll
    for (int c = 0; c < NCHUNKS; ++c)
        xs[c] = src[((size_t)(c * BPB + bx)) * CHUNK + col];

    // zero both tiles once (2*4624/8 = 1156 b128)
    {
        i32x4 z = {0, 0, 0, 0};
        i32x4* zp = (i32x4*)smem;
#pragma unroll
        for (int i = 0; i < 5; ++i) {
            int idx = i * NTHREADS + tid;
            if (idx < (2 * TILE_HALVES) / 8) zp[idx] = z;
        }
    }

    f32x16 acc;
#pragma unroll
    for (int r = 0; r < 16; ++r) acc[r] = 0.0f;

    int kb_old = 0;

#define DO_MFMA() { \
        _Pragma("unroll") \
        for (int kk = 0; kk < 2; ++kk) { \
            half8 af = *(const half8*)&TA[frag + kk * 16]; \
            half8 bf = *(const half8*)&TB[frag + kk * 16]; \
            acc = __builtin_amdgcn_mfma_f32_32x32x16_f16(af, bf, acc, 0, 0, 0); \
        } }

    // chunk 0 (no stale taps yet)
    {
        _Float16 wq[6]; int kb;
        compute_w(xs[0], kb, wq);
        __syncthreads();                 // prologue zero visible
        scatter6(T, col, kb, wq);
        kb_old = kb;
        __syncthreads();                 // scatter visible
        DO_MFMA();
    }
#pragma unroll
    for (int c = 1; c < NCHUNKS; ++c) {
        _Float16 wq[6]; int kb;
        compute_w(xs[c], kb, wq);        // VALU overlaps MFMA pipe + other blocks' LDS phases
        __syncthreads();                 // prev MFMA ds_reads drained (WAR safe)
        zero6(T, col, kb_old);           // stale taps from chunk c-1
        scatter6(T, col, kb, wq);
        kb_old = kb;
        __syncthreads();                 // scatter visible
        DO_MFMA();
    }
    __syncthreads();                     // last MFMA reads drained before smem reuse

    // block reduce: 4 waves hold K-split partials of the SAME 32x32.
    // C/D layout (32x32): col = lane&31, row = (reg&3) + 8*(reg>>2) + 4*(lane>>5)
    float* red = (float*)smem;           // 4 * 1024 floats = 16 KB (fits 18.5 KB)
    const int colc = lane & 31;
    const int rlo = 4 * (lane >> 5);
#pragma unroll
    for (int r = 0; r < 16; ++r) {
        int rowc = (r & 3) + 8 * (r >> 2) + rlo;
        red[wid * 1024 + rowc * 32 + colc] = acc[r];
    }
    __syncthreads();
    float* H = hist + ((size_t)(bx & (NSLOTS - 1)) * 2 + batch) * 1024;
    for (int idx = tid; idx < 1024; idx += NTHREADS) {
        float s = red[idx] + red[1024 + idx] + red[2048 + idx] + red[3072 + idx];
        atomicAdd(&H[idx], s);
    }
}

__global__ void mi_reduce_kernel(const float* __restrict__ hist, float* __restrict__ out) {
    __shared__ float s_pab[2 * NBINS * NBINS];
    __shared__ double s_pa[2][NBINS];
    __shared__ double s_pb[2][NBINS];
    __shared__ double s_red[1024];
    const int tid = threadIdx.x;
    const double invN = 1.0 / (double)NVOX;

    for (int g = tid; g < 512; g += 1024) {
        float4 s = make_float4(0.f, 0.f, 0.f, 0.f);
        for (int sl = 0; sl < NSLOTS; ++sl) {
            float4 v = ((const float4*)hist)[sl * 512 + g];
            s.x += v.x; s.y += v.y; s.z += v.z; s.w += v.w;
        }
        ((float4*)s_pab)[g] = s;
    }
    __syncthreads();

    if (tid < 64) {
        int b = tid >> 5, i = tid & 31;
        double s = 0.0;
        for (int j = 0; j < NBINS; ++j) s += (double)s_pab[(b * NBINS + i) * NBINS + j];
        s_pa[b][i] = s * invN;
    } else if (tid < 128) {
        int t2 = tid - 64;
        int b = t2 >> 5, j = t2 & 31;
        double s = 0.0;
        for (int i = 0; i < NBINS; ++i) s += (double)s_pab[(b * NBINS + i) * NBINS + j];
        s_pb[b][j] = s * invN;
    }
    __syncthreads();

    double acc = 0.0;
    for (int idx = tid; idx < 2 * NBINS * NBINS; idx += 1024) {
        int b = idx >> 10;
        int cell = idx & 1023;
        int i = cell >> 5, j = cell & 31;
        double pab = (double)s_pab[idx] * invN;
        double papb = s_pa[b][i] * s_pb[b][j];
        acc += pab * log((pab + 1e-7) / (papb + 1e-7) + 1e-7);
    }
    s_red[tid] = acc;
    __syncthreads();
    for (int s2 = 512; s2 > 0; s2 >>= 1) {
        if (tid < s2) s_red[tid] += s_red[tid + s2];
        __syncthreads();
    }
    if (tid == 0) out[0] = (float)(-0.5 * s_red[0]);
}

extern "C" void kernel_launch(void* const* d_in, const int* in_sizes, int n_in,
                              void* d_out, int out_size, void* d_ws, size_t ws_size,
                              hipStream_t stream) {
    const float* pred = (const float*)d_in[0];
    const float* targ = (const float*)d_in[1];
    float* hist = (float*)d_ws;
    float* out = (float*)d_out;

    hipMemsetAsync(hist, 0, NSLOTS * 2 * NBINS * NBINS * sizeof(float), stream);
    dim3 grid(BPB, 2);
    hipLaunchKernelGGL(mi_hist_kernel, grid, dim3(NTHREADS), 0, stream, pred, targ, hist);
    hipLaunchKernelGGL(mi_reduce_kernel, dim3(1), dim3(1024), 0, stream, hist, out);
}